// Round 10
// baseline (245.821 us; speedup 1.0000x reference)
//
#include <hip/hip_runtime.h>
#include <hip/hip_bf16.h>

// Problem dims (fixed by reference setup_inputs)
#define M_DIM 32
#define K_DIM 8192
#define N_DIM 8192
#define KS 16                        // k-split slices
#define KCH (K_DIM / KS)             // 512 k per block
#define CHK 128                      // k per pipelined chunk
#define NCHK (KCH / CHK)             // 4 chunks
#define STEPS (CHK / 32)             // 4 MFMA k-steps per chunk
#define NPB 128                      // n-cols per block
#define NBLK (N_DIM / NPB)           // 64
#define MAIN_BLOCKS (NBLK * KS)      // 1024

#define QW_ROWI4 (K_DIM / 8)         // 1024 int4 per qweight row
#define SC_ROW (K_DIM / 16)          // 512 f32 per scales row

// LDS strides
#define QROW 20                      // dwords per Q row (16 + 4 pad; 16B-aligned)
#define AROW 136                     // f16 per A row (128 + 8)
#define SROW 9                       // f32 per S row (8 + 1)

#define QP_TILE_U4 512               // uint4 per (nb,ks,chunk) packed-Q tile

typedef _Float16 half8   __attribute__((ext_vector_type(8)));
typedef _Float16 half4_t __attribute__((ext_vector_type(4)));
typedef float    floatx4 __attribute__((ext_vector_type(4)));

// ---- Proven E2M1 bit-decode (R1/R6/R8 pedigree, absmax 2.0) ----
__device__ __forceinline__ uint32_t dec2(uint32_t b) {
  uint32_t c0 = b & 0xFu, c1 = (b >> 4) & 0xFu;
  uint32_t m0 = c0 & 7u, m1 = c1 & 7u;
  uint32_t t0 = min(28u * m0, m0 + 28u);
  uint32_t t1 = min(28u * m1, m1 + 28u);
  return (t0 << 9) | ((c0 & 8u) << 12)
       | (t1 << 25) | ((c1 & 8u) << 28);
}

// Packed dword (4 payload bytes = 8 fp4 along k) -> 8 f16, times f16 scale.
__device__ __forceinline__ half8 decode8p(uint32_t q, _Float16 s) {
  union { uint32_t u[4]; half8 h; } w;
  w.u[0] = dec2(q & 0xFFu);
  w.u[1] = dec2((q >> 8) & 0xFFu);
  w.u[2] = dec2((q >> 16) & 0xFFu);
  w.u[3] = dec2((q >> 24) & 0xFFu);
  half8 sv = {s, s, s, s, s, s, s, s};
  return w.h * sv;
}

__device__ __forceinline__ uint32_t pack4(int4 v) {
  return ((uint32_t)v.x & 0xFFu) | (((uint32_t)v.y & 0xFFu) << 8)
       | (((uint32_t)v.z & 0xFFu) << 16) | (((uint32_t)v.w & 0xFFu) << 24);
}

// ---- Repack: qweight 134 MB int32 -> 33.5 MB packed nibbles, tiled in the
// exact (nb, ks, chunk, thread) order the main kernel stages. Pure stream:
// per-thread 64 B contiguous read, write fully linear. Doubles as the pure-
// read-rate probe (its hbm_gbps = the machine's streaming read ceiling).
__global__ __launch_bounds__(256) void repack_kernel(
    const int4* __restrict__ qw4, uint4* __restrict__ qp) {
  const int g  = blockIdx.x * 256 + threadIdx.x;  // [0, 2^21)
  const int u  = g & 511;                         // uint4 within tile
  const int c  = (g >> 9) & 3;                    // chunk
  const int ks = (g >> 11) & 15;                  // k-slice
  const int nb = g >> 15;                         // n-block [0,64)
  const int r  = u >> 2, c4 = u & 3;              // row in tile, col quarter
  const int4* src = qw4 + (size_t)(nb * NPB + r) * QW_ROWI4
                  + ks * (KCH / 8) + c * (CHK / 8) + c4 * 4;
  int4 a = src[0], b = src[1], cc = src[2], d = src[3];
  uint4 o;
  o.x = pack4(a); o.y = pack4(b); o.z = pack4(cc); o.w = pack4(d);
  qp[g] = o;
}

// inp f32 -> ws f16 (once; 512 KB)
__global__ void convertA_kernel(const floatx4* __restrict__ in4,
                                half4_t* __restrict__ out4) {
  int idx = blockIdx.x * blockDim.x + threadIdx.x;
  floatx4 f = in4[idx];
  half4_t h;
  h[0] = (_Float16)f[0]; h[1] = (_Float16)f[1];
  h[2] = (_Float16)f[2]; h[3] = (_Float16)f[3];
  out4[idx] = h;
}

// out = bias + sum of KS partial slabs
__global__ void reduce_kernel(const floatx4* __restrict__ part,
                              const floatx4* __restrict__ bias4,
                              floatx4* __restrict__ out4) {
  int idx = blockIdx.x * blockDim.x + threadIdx.x;   // [0, 65536)
  floatx4 acc = bias4[idx & (N_DIM / 4 - 1)];
#pragma unroll
  for (int s = 0; s < KS; ++s)
    acc += part[(size_t)s * (M_DIM * N_DIM / 4) + idx];
  out4[idx] = acc;
}

// out[m][n] = bias[n] (fallback path)
__global__ void init_out_kernel(floatx4* __restrict__ out4,
                                const floatx4* __restrict__ bias4) {
  int idx = blockIdx.x * blockDim.x + threadIdx.x;
  out4[idx] = bias4[idx & (N_DIM / 4 - 1)];
}

// ---- Main: R8 chunk-pipelined skeleton; Q from packed tiles (4x less). ----
__global__ __launch_bounds__(256, 4) void fp4_linear_packed(
    const _Float16* __restrict__ Af16,   // [32][8192] f16 (ws)
    const uint4*    __restrict__ qp,     // packed tiles (ws)
    const float*    __restrict__ scales, // [8192, 512] f32
    const float*    __restrict__ amaxp,  // [1]
    float*          __restrict__ part)   // [KS][32][8192] f32 partial slabs
{
  __shared__ uint32_t Qs[NPB * QROW];     // 10240 B
  __shared__ _Float16 As[M_DIM * AROW];   //  8704 B
  __shared__ float    Ss[NPB * SROW];     //  4608 B  -> 23552 B, 4 blk/CU

  const int t    = threadIdx.x;
  const int lane = t & 63;
  const int w    = t >> 6;
  const int ks   = blockIdx.x & (KS - 1);
  const int nb   = blockIdx.x >> 4;
  const int n0   = nb * NPB;
  const int kb   = ks * KCH;
  const float amax = amaxp[0];

  const uint4* qtile = qp + (size_t)((nb * 16 + ks) * 4) * QP_TILE_U4;
  const int ar = t >> 4, ac = t & 15;     // A: rows j*16+ar, half8-col ac
  const _Float16* asrc = Af16 + (size_t)ar * K_DIM + kb + ac * 8;
  const int sr = t >> 1, sh = t & 1;      // S: 128 rows x 2 float4
  const float* ssrc = scales + (size_t)(n0 + sr) * SC_ROW + ks * (KCH / 16) + sh * 4;

  uint4   qreg[2];
  half8   areg[2];
  floatx4 sreg;

  // preload chunk 0 (fully linear 1 KB wave-bursts for Q)
  qreg[0] = qtile[t];
  qreg[1] = qtile[256 + t];
  areg[0] = *(const half8*)asrc;
  areg[1] = *(const half8*)(asrc + (size_t)16 * K_DIM);
  sreg = *(const floatx4*)ssrc;

  const int row  = lane & 15;
  const int quad = lane >> 4;
  const int nloc = w * 32;
  const uint32_t* qAp = &Qs[(nloc + row) * QROW];
  const uint32_t* qBp = &Qs[(nloc + 16 + row) * QROW];
  const _Float16* a0p = &As[row * AROW];
  const _Float16* a1p = &As[(row + 16) * AROW];
  const float*    sAp = &Ss[(nloc + row) * SROW];
  const float*    sBp = &Ss[(nloc + 16 + row) * SROW];

  floatx4 acc00 = {0.f, 0.f, 0.f, 0.f};
  floatx4 acc01 = {0.f, 0.f, 0.f, 0.f};
  floatx4 acc10 = {0.f, 0.f, 0.f, 0.f};
  floatx4 acc11 = {0.f, 0.f, 0.f, 0.f};

  for (int c = 0; c < NCHK; ++c) {
    if (c) __syncthreads();

    // store staged regs -> LDS
#pragma unroll
    for (int j = 0; j < 2; ++j) {
      const int u = j * 256 + t;            // [0, 512)
      const int r = u >> 2, c4 = u & 3;
      *(uint4*)&Qs[r * QROW + c4 * 4] = qreg[j];  // 16B-aligned (QROW=20)
      *(half8*)&As[(j * 16 + ar) * AROW + ac * 8] = areg[j];
    }
    {
      float* sd = &Ss[sr * SROW + sh * 4];
      sd[0] = sreg[0] * amax; sd[1] = sreg[1] * amax;
      sd[2] = sreg[2] * amax; sd[3] = sreg[3] * amax;
    }
    __syncthreads();

    // issue next chunk's loads (in flight during compute)
    if (c + 1 < NCHK) {
      const int c1 = c + 1;
      qreg[0] = qtile[c1 * QP_TILE_U4 + t];
      qreg[1] = qtile[c1 * QP_TILE_U4 + 256 + t];
      areg[0] = *(const half8*)(asrc + c1 * CHK);
      areg[1] = *(const half8*)(asrc + (size_t)16 * K_DIM + c1 * CHK);
      sreg = *(const floatx4*)(ssrc + c1 * (CHK / 16));
    }

    // compute chunk c from LDS (identical semantics to R8)
#pragma unroll
    for (int it = 0; it < STEPS; ++it) {
      const uint32_t qA = qAp[it * 4 + quad];
      const uint32_t qB = qBp[it * 4 + quad];
      const _Float16 sA = (_Float16)sAp[it * 2 + (quad >> 1)];
      const _Float16 sB = (_Float16)sBp[it * 2 + (quad >> 1)];
      half8 bA = decode8p(qA, sA);
      half8 bB = decode8p(qB, sB);
      half8 a0 = *(const half8*)(a0p + it * 32 + quad * 8);
      half8 a1 = *(const half8*)(a1p + it * 32 + quad * 8);
      acc00 = __builtin_amdgcn_mfma_f32_16x16x32_f16(a0, bA, acc00, 0, 0, 0);
      acc01 = __builtin_amdgcn_mfma_f32_16x16x32_f16(a0, bB, acc01, 0, 0, 0);
      acc10 = __builtin_amdgcn_mfma_f32_16x16x32_f16(a1, bA, acc10, 0, 0, 0);
      acc11 = __builtin_amdgcn_mfma_f32_16x16x32_f16(a1, bB, acc11, 0, 0, 0);
    }
  }

  // Epilogue: partial slab store. D: col(n)=lane&15, row(m)=quad*4+reg.
  float* pb = part + (size_t)ks * (M_DIM * N_DIM);
#pragma unroll
  for (int r = 0; r < 4; ++r) {
    const int m = quad * 4 + r;
    float* o0 = pb + (size_t)m * N_DIM + n0 + nloc;
    float* o1 = pb + (size_t)(m + 16) * N_DIM + n0 + nloc;
    o0[row]      = acc00[r];
    o0[16 + row] = acc01[r];
    o1[row]      = acc10[r];
    o1[16 + row] = acc11[r];
  }
}

// ---- Fallback (tiny ws): R6-style direct kernel with atomic epilogue. ----
__global__ __launch_bounds__(256, 4) void fp4_linear_fallback(
    const float* __restrict__ inp, const int4* __restrict__ qw4,
    const float* __restrict__ scales, const float* __restrict__ amaxp,
    float* __restrict__ out) {
  const int t = threadIdx.x, lane = t & 63, w = t >> 6;
  const int ks = blockIdx.x & (KS - 1), nb = blockIdx.x >> 4;
  const int n0 = nb * NPB, kb = ks * KCH;
  const float amax = amaxp[0];
  const int row = lane & 15, quad = lane >> 4, nloc = w * 32;
  const int nA = n0 + nloc + row, nB = nA + 16;
  const int4* qrowA = qw4 + (size_t)nA * QW_ROWI4;
  const int4* qrowB = qw4 + (size_t)nB * QW_ROWI4;
  const float* srowA = scales + (size_t)nA * SC_ROW;
  const float* srowB = scales + (size_t)nB * SC_ROW;
  floatx4 acc00 = {0,0,0,0}, acc01 = {0,0,0,0}, acc10 = {0,0,0,0}, acc11 = {0,0,0,0};
  for (int k0 = kb; k0 < kb + KCH; k0 += 32) {
    const int kq = k0 + quad * 8;
    int4 qA = qrowA[kq >> 3], qB = qrowB[kq >> 3];
    _Float16 sA = (_Float16)(srowA[kq >> 4] * amax);
    _Float16 sB = (_Float16)(srowB[kq >> 4] * amax);
    half8 bA = decode8p(pack4(qA), sA);
    half8 bB = decode8p(pack4(qB), sB);
    half8 a0, a1;
    const float* ap0 = inp + (size_t)row * K_DIM + kq;
    const float* ap1 = ap0 + (size_t)16 * K_DIM;
#pragma unroll
    for (int i = 0; i < 8; ++i) { a0[i] = (_Float16)ap0[i]; a1[i] = (_Float16)ap1[i]; }
    acc00 = __builtin_amdgcn_mfma_f32_16x16x32_f16(a0, bA, acc00, 0, 0, 0);
    acc01 = __builtin_amdgcn_mfma_f32_16x16x32_f16(a0, bB, acc01, 0, 0, 0);
    acc10 = __builtin_amdgcn_mfma_f32_16x16x32_f16(a1, bA, acc10, 0, 0, 0);
    acc11 = __builtin_amdgcn_mfma_f32_16x16x32_f16(a1, bB, acc11, 0, 0, 0);
  }
#pragma unroll
  for (int r = 0; r < 4; ++r) {
    const int m = quad * 4 + r;
    float* o0 = out + (size_t)m * N_DIM + n0 + nloc;
    float* o1 = out + (size_t)(m + 16) * N_DIM + n0 + nloc;
    unsafeAtomicAdd(o0 + row,      acc00[r]);
    unsafeAtomicAdd(o0 + 16 + row, acc01[r]);
    unsafeAtomicAdd(o1 + row,      acc10[r]);
    unsafeAtomicAdd(o1 + 16 + row, acc11[r]);
  }
}

extern "C" void kernel_launch(void* const* d_in, const int* in_sizes, int n_in,
                              void* d_out, int out_size, void* d_ws, size_t ws_size,
                              hipStream_t stream) {
  const float* inp    = (const float*)d_in[0];
  const int4*  qw4    = (const int4*)d_in[1];
  const float* scales = (const float*)d_in[2];
  const float* amaxp  = (const float*)d_in[3];
  const float* bias   = (const float*)d_in[4];
  float* out = (float*)d_out;

  const size_t part_bytes = (size_t)KS * M_DIM * N_DIM * sizeof(float);   // 16.8 MB
  const size_t a16_bytes  = (size_t)M_DIM * K_DIM * sizeof(_Float16);     // 512 KB
  const size_t qp_bytes   = (size_t)N_DIM * (K_DIM / 8) * 4;              // 33.5 MB

  if (ws_size >= part_bytes + a16_bytes + qp_bytes) {
    float*    partp = (float*)d_ws;
    _Float16* Af16  = (_Float16*)((char*)d_ws + part_bytes);
    uint4*    qp    = (uint4*)((char*)d_ws + part_bytes + a16_bytes);
    repack_kernel<<<8192, 256, 0, stream>>>(qw4, qp);
    convertA_kernel<<<M_DIM * K_DIM / 4 / 256, 256, 0, stream>>>(
        (const floatx4*)inp, (half4_t*)Af16);
    fp4_linear_packed<<<MAIN_BLOCKS, 256, 0, stream>>>(
        Af16, qp, scales, amaxp, partp);
    reduce_kernel<<<M_DIM * N_DIM / 4 / 256, 256, 0, stream>>>(
        (const floatx4*)partp, (const floatx4*)bias, (floatx4*)out);
  } else {
    init_out_kernel<<<M_DIM * N_DIM / 4 / 256, 256, 0, stream>>>(
        (floatx4*)out, (const floatx4*)bias);
    fp4_linear_fallback<<<MAIN_BLOCKS, 256, 0, stream>>>(
        inp, qw4, scales, amaxp, out);
  }
}